// Round 9
// baseline (180.996 us; speedup 1.0000x reference)
//
#include <hip/hip_runtime.h>

#define N_SEQ 4140
#define NP    4160          // padded N (130*32)
#define C_IN  256
#define HEADS 8
#define NT32  130
#define HN    (HEADS * N_SEQ)
#define LOG2E 1.4426950408889634f
#define SCALE2 (0.17677669529663687f * LOG2E)   // (1/sqrt(32)) * log2e
#define INVSCALE 5.656854249492381f             // sqrt(32)

typedef _Float16 f16x8 __attribute__((ext_vector_type(8)));
typedef float    f32x16 __attribute__((ext_vector_type(16)));

__device__ inline unsigned short f16b(float x) {
    union { _Float16 h; unsigned short s; } c;
    c.h = (_Float16)x;
    return c.s;
}
__device__ inline unsigned pack2h(float lo, float hi) {
    union { _Float16 h[2]; unsigned u; } c;
    c.h[0] = (_Float16)lo;
    c.h[1] = (_Float16)hi;
    return c.u;
}
__device__ inline void permswap(unsigned &a, unsigned &b) {
    asm volatile("v_permlane32_swap_b32 %0, %1" : "+v"(a), "+v"(b));
}

// ---------------------------------------------------------------------------
// prep: blocks x<130: x[c][n] f32 -> xt[n][c] f16 (zero-pad n>=N_SEQ).
//       blocks x>=130: weight f16 conversion, lw2 = log_qw*INVSCALE (pad -1e30)
// grid: (133, 8) x 256
// ---------------------------------------------------------------------------
__global__ __launch_bounds__(256) void prep_kernel(
    const float* __restrict__ x, const float* __restrict__ log_qw,
    const float* __restrict__ q_w, const float* __restrict__ k_w,
    const float* __restrict__ v_w, const float* __restrict__ p_w,
    unsigned short* __restrict__ xt, float* __restrict__ lw2,
    unsigned short* __restrict__ wf, unsigned short* __restrict__ pwf)
{
    if (blockIdx.x < NT32) {
        __shared__ unsigned short tile[32][33];
        const int tx = threadIdx.x & 31, ty = threadIdx.x >> 5;
        const int n0 = blockIdx.x * 32, c0 = blockIdx.y * 32;
#pragma unroll
        for (int i = 0; i < 4; ++i) {
            const int c = c0 + ty * 4 + i;
            const int n = n0 + tx;
            const float v = (n < N_SEQ) ? x[(size_t)c * N_SEQ + n] : 0.f;
            tile[tx][ty * 4 + i] = f16b(v);
        }
        __syncthreads();
#pragma unroll
        for (int i = 0; i < 4; ++i) {
            const int nl = ty * 4 + i;
            xt[(size_t)(n0 + nl) * C_IN + c0 + tx] = tile[nl][tx];
        }
    } else {
        const int bid = (blockIdx.x - NT32) * 8 + blockIdx.y;   // 0..23
        for (int i = bid * 256 + threadIdx.x; i < 262144 + NP; i += 24 * 256) {
            if (i < 65536)        wf[i] = f16b(q_w[i]);
            else if (i < 131072)  wf[i] = f16b(k_w[i - 65536]);
            else if (i < 196608)  wf[i] = f16b(v_w[i - 131072]);
            else if (i < 262144)  pwf[i - 196608] = f16b(p_w[i - 196608]);
            else {
                const int j = i - 262144;
                lw2[j] = (j < N_SEQ) ? log_qw[j] * INVSCALE : -1e30f;
            }
        }
    }
}

// ---------------------------------------------------------------------------
// qkv_mfma: 24 oc-tiles x 65 n-pair-tiles, 1 wave each; two independent
// 16-MFMA chains sharing one operand. q,k -> [h][n][32] ;
// v -> [((h*130+t)*32+d)*32+klocal].  grid: 390 x 256
// ---------------------------------------------------------------------------
__global__ __launch_bounds__(256) void qkv_mfma(
    const unsigned short* __restrict__ xt, const unsigned short* __restrict__ wf,
    const float* __restrict__ q_b, const float* __restrict__ k_b,
    const float* __restrict__ v_b,
    unsigned short* __restrict__ qo, unsigned short* __restrict__ ko,
    unsigned short* __restrict__ vo)
{
    const int tid = threadIdx.x, wid = tid >> 6, lane = tid & 63;
    const int col = lane & 31, hi = lane >> 5;
    const int w = blockIdx.x * 4 + wid;          // 0..1559
    const int ot = w / 65, pt = w % 65;
    const int n0 = pt * 64, n1 = n0 + 32;

    if (ot < 16) {
        const unsigned short* a0 = xt + (size_t)(n0 + col) * C_IN + hi * 8;
        const unsigned short* a1 = xt + (size_t)(n1 + col) * C_IN + hi * 8;
        const unsigned short* bw = wf + (size_t)(ot * 32 + col) * C_IN + hi * 8;
        const float bias = (ot < 8) ? q_b[ot * 32 + col] : k_b[(ot - 8) * 32 + col];
        f32x16 acc0, acc1;
#pragma unroll
        for (int r = 0; r < 16; ++r) { acc0[r] = bias; acc1[r] = bias; }
#pragma unroll
        for (int t = 0; t < 16; ++t) {
            const f16x8 bf  = *(const f16x8*)(const void*)(bw + t * 16);
            const f16x8 af0 = *(const f16x8*)(const void*)(a0 + t * 16);
            const f16x8 af1 = *(const f16x8*)(const void*)(a1 + t * 16);
            acc0 = __builtin_amdgcn_mfma_f32_32x32x16_f16(af0, bf, acc0, 0, 0, 0);
            acc1 = __builtin_amdgcn_mfma_f32_32x32x16_f16(af1, bf, acc1, 0, 0, 0);
        }
        unsigned short* dst = (ot < 8) ? qo : ko;
        const int h = ot & 7;
#pragma unroll
        for (int r = 0; r < 16; ++r) {
            const int rl = (r & 3) + 8 * (r >> 2) + 4 * hi;
            dst[(size_t)(h * NP + n0 + rl) * 32 + col] = f16b(acc0[r]);
            dst[(size_t)(h * NP + n1 + rl) * 32 + col] = f16b(acc1[r]);
        }
    } else {
        const int h = ot - 16;
        const unsigned short* aw = wf + (size_t)(512 + h * 32 + col) * C_IN + hi * 8;
        const unsigned short* b0 = xt + (size_t)(n0 + col) * C_IN + hi * 8;
        const unsigned short* b1 = xt + (size_t)(n1 + col) * C_IN + hi * 8;
        const float* vb4 = v_b + h * 32 + 4 * hi;
        const float4 c0 = *(const float4*)(vb4);
        const float4 c1 = *(const float4*)(vb4 + 8);
        const float4 c2 = *(const float4*)(vb4 + 16);
        const float4 c3 = *(const float4*)(vb4 + 24);
        f32x16 acc0;
        acc0[0]=c0.x; acc0[1]=c0.y; acc0[2]=c0.z; acc0[3]=c0.w;
        acc0[4]=c1.x; acc0[5]=c1.y; acc0[6]=c1.z; acc0[7]=c1.w;
        acc0[8]=c2.x; acc0[9]=c2.y; acc0[10]=c2.z; acc0[11]=c2.w;
        acc0[12]=c3.x; acc0[13]=c3.y; acc0[14]=c3.z; acc0[15]=c3.w;
        f32x16 acc1 = acc0;
#pragma unroll
        for (int t = 0; t < 16; ++t) {
            const f16x8 af  = *(const f16x8*)(const void*)(aw + t * 16);
            const f16x8 bf0 = *(const f16x8*)(const void*)(b0 + t * 16);
            const f16x8 bf1 = *(const f16x8*)(const void*)(b1 + t * 16);
            acc0 = __builtin_amdgcn_mfma_f32_32x32x16_f16(af, bf0, acc0, 0, 0, 0);
            acc1 = __builtin_amdgcn_mfma_f32_32x32x16_f16(af, bf1, acc1, 0, 0, 0);
        }
        const int nt0 = pt * 2, nt1 = nt0 + 1;
#pragma unroll
        for (int r = 0; r < 16; ++r) {
            const int d = (r & 3) + 8 * (r >> 2) + 4 * hi;
            vo[((size_t)(h * NT32 + nt0) * 32 + d) * 32 + col] = f16b(acc0[r]);
            vo[((size_t)(h * NT32 + nt1) * 32 + d) * 32 + col] = f16b(acc1[r]);
        }
    }
}

// ---------------------------------------------------------------------------
// MFMA flash attention, round-7 numerics (defer-max, log2 domain), TWO
// q-tiles per wave (independent chains, shared K/V/lw loads).
// grid: (130, nz) x 256 ; wave = (head, q-pair-tile)
// ---------------------------------------------------------------------------
__global__ __launch_bounds__(256) void attn_mfma_kernel(
    const unsigned short* __restrict__ qb, const unsigned short* __restrict__ kb,
    const unsigned short* __restrict__ vb, const float* __restrict__ lw2,
    float* __restrict__ pm, float* __restrict__ pl, float* __restrict__ pacc,
    int tiles_per_z)
{
    const int tid = threadIdx.x;
    const int wid = tid >> 6;
    const int lane = tid & 63;
    const int col = lane & 31;
    const int hi = lane >> 5;
    const int job = blockIdx.x * 4 + wid;   // 0..519
    const int h = job / 65;
    const int pt = job % 65;
    const int z = blockIdx.y;

    const int qrowA = pt * 64 + col;
    const int qrowB = qrowA + 32;
    const unsigned short* qpA = qb + ((size_t)(h * NP + qrowA)) * 32 + hi * 8;
    const unsigned short* qpB = qb + ((size_t)(h * NP + qrowB)) * 32 + hi * 8;
    const f16x8 qfA0 = *(const f16x8*)(const void*)(qpA);
    const f16x8 qfA1 = *(const f16x8*)(const void*)(qpA + 16);
    const f16x8 qfB0 = *(const f16x8*)(const void*)(qpB);
    const f16x8 qfB1 = *(const f16x8*)(const void*)(qpB + 16);

    f32x16 oA, oB;
#pragma unroll
    for (int r = 0; r < 16; ++r) { oA[r] = 0.f; oB[r] = 0.f; }
    float mA = -1e30f, lsA = 0.f;
    float mB = -1e30f, lsB = 0.f;

    const int t0 = z * tiles_per_z;
    const int t1 = min(NT32, t0 + tiles_per_z);
    const unsigned short* kbase = kb + (size_t)h * NP * 32;
    const unsigned short* vbase = vb + (size_t)h * NT32 * 1024;

    for (int t = t0; t < t1; ++t) {
        const int k0 = t * 32;
        const unsigned short* kp = kbase + (size_t)(k0 + col) * 32 + hi * 8;
        const f16x8 ka0 = *(const f16x8*)(const void*)(kp);
        const f16x8 ka1 = *(const f16x8*)(const void*)(kp + 16);
        const unsigned short* vp = vbase + (size_t)t * 1024 + col * 32 + hi * 8;
        const f16x8 va0 = *(const f16x8*)(const void*)(vp);
        const f16x8 va1 = *(const f16x8*)(const void*)(vp + 16);

        const float* lw4 = lw2 + k0 + 4 * hi;
        const float4 w0 = *(const float4*)(lw4);
        const float4 w1 = *(const float4*)(lw4 + 8);
        const float4 w2 = *(const float4*)(lw4 + 16);
        const float4 w3 = *(const float4*)(lw4 + 24);
        f32x16 sI;
        sI[0]=w0.x; sI[1]=w0.y; sI[2]=w0.z; sI[3]=w0.w;
        sI[4]=w1.x; sI[5]=w1.y; sI[6]=w1.z; sI[7]=w1.w;
        sI[8]=w2.x; sI[9]=w2.y; sI[10]=w2.z; sI[11]=w2.w;
        sI[12]=w3.x; sI[13]=w3.y; sI[14]=w3.z; sI[15]=w3.w;

        f32x16 sA = sI, sB = sI;
        sA = __builtin_amdgcn_mfma_f32_32x32x16_f16(ka0, qfA0, sA, 0, 0, 0);
        sB = __builtin_amdgcn_mfma_f32_32x32x16_f16(ka0, qfB0, sB, 0, 0, 0);
        sA = __builtin_amdgcn_mfma_f32_32x32x16_f16(ka1, qfA1, sA, 0, 0, 0);
        sB = __builtin_amdgcn_mfma_f32_32x32x16_f16(ka1, qfB1, sB, 0, 0, 0);

        float pA[16], pB[16];
#pragma unroll
        for (int r = 0; r < 16; ++r) { pA[r] = sA[r] * SCALE2; pB[r] = sB[r] * SCALE2; }

        // independent lane-local max trees
        float ax0 = fmaxf(pA[0], pA[1]),   ax1 = fmaxf(pA[2], pA[3]);
        float ax2 = fmaxf(pA[4], pA[5]),   ax3 = fmaxf(pA[6], pA[7]);
        float ax4 = fmaxf(pA[8], pA[9]),   ax5 = fmaxf(pA[10], pA[11]);
        float ax6 = fmaxf(pA[12], pA[13]), ax7 = fmaxf(pA[14], pA[15]);
        float bx0 = fmaxf(pB[0], pB[1]),   bx1 = fmaxf(pB[2], pB[3]);
        float bx2 = fmaxf(pB[4], pB[5]),   bx3 = fmaxf(pB[6], pB[7]);
        float bx4 = fmaxf(pB[8], pB[9]),   bx5 = fmaxf(pB[10], pB[11]);
        float bx6 = fmaxf(pB[12], pB[13]), bx7 = fmaxf(pB[14], pB[15]);
        ax0 = fmaxf(ax0, ax1); ax2 = fmaxf(ax2, ax3);
        ax4 = fmaxf(ax4, ax5); ax6 = fmaxf(ax6, ax7);
        bx0 = fmaxf(bx0, bx1); bx2 = fmaxf(bx2, bx3);
        bx4 = fmaxf(bx4, bx5); bx6 = fmaxf(bx6, bx7);
        const float cmaxA = fmaxf(fmaxf(ax0, ax2), fmaxf(ax4, ax6));
        const float cmaxB = fmaxf(fmaxf(bx0, bx2), fmaxf(bx4, bx6));

        if (!__all(cmaxA - mA <= 8.0f)) {
            float cw = fmaxf(cmaxA, __shfl_xor(cmaxA, 32));
            const float mnew = fmaxf(mA, cw);
            const float esc = __builtin_amdgcn_exp2f(mA - mnew);
            lsA *= esc;
#pragma unroll
            for (int r = 0; r < 16; ++r) oA[r] *= esc;
            mA = mnew;
        }
        if (!__all(cmaxB - mB <= 8.0f)) {
            float cw = fmaxf(cmaxB, __shfl_xor(cmaxB, 32));
            const float mnew = fmaxf(mB, cw);
            const float esc = __builtin_amdgcn_exp2f(mB - mnew);
            lsB *= esc;
#pragma unroll
            for (int r = 0; r < 16; ++r) oB[r] *= esc;
            mB = mnew;
        }

#pragma unroll
        for (int r = 0; r < 16; ++r) {
            pA[r] = __builtin_amdgcn_exp2f(pA[r] - mA);
            pB[r] = __builtin_amdgcn_exp2f(pB[r] - mB);
        }
        {
            float s0 = (pA[0] + pA[1]) + (pA[2] + pA[3]);
            float s1 = (pA[4] + pA[5]) + (pA[6] + pA[7]);
            float s2 = (pA[8] + pA[9]) + (pA[10] + pA[11]);
            float s3 = (pA[12] + pA[13]) + (pA[14] + pA[15]);
            lsA += (s0 + s1) + (s2 + s3);
            float u0 = (pB[0] + pB[1]) + (pB[2] + pB[3]);
            float u1 = (pB[4] + pB[5]) + (pB[6] + pB[7]);
            float u2 = (pB[8] + pB[9]) + (pB[10] + pB[11]);
            float u3 = (pB[12] + pB[13]) + (pB[14] + pB[15]);
            lsB += (u0 + u1) + (u2 + u3);
        }

        union U { unsigned u[4]; f16x8 v; };
        // stream A
        {
            unsigned a0 = pack2h(pA[0], pA[1]),  b0 = pack2h(pA[2], pA[3]);
            unsigned c0 = pack2h(pA[4], pA[5]),  d0 = pack2h(pA[6], pA[7]);
            permswap(a0, c0); permswap(b0, d0);
            U pb0; pb0.u[0]=a0; pb0.u[1]=b0; pb0.u[2]=c0; pb0.u[3]=d0;
            oA = __builtin_amdgcn_mfma_f32_32x32x16_f16(va0, pb0.v, oA, 0, 0, 0);
            unsigned e0 = pack2h(pA[8], pA[9]),   f0 = pack2h(pA[10], pA[11]);
            unsigned g0 = pack2h(pA[12], pA[13]), h0 = pack2h(pA[14], pA[15]);
            permswap(e0, g0); permswap(f0, h0);
            U pb1; pb1.u[0]=e0; pb1.u[1]=f0; pb1.u[2]=g0; pb1.u[3]=h0;
            oA = __builtin_amdgcn_mfma_f32_32x32x16_f16(va1, pb1.v, oA, 0, 0, 0);
        }
        // stream B
        {
            unsigned a0 = pack2h(pB[0], pB[1]),  b0 = pack2h(pB[2], pB[3]);
            unsigned c0 = pack2h(pB[4], pB[5]),  d0 = pack2h(pB[6], pB[7]);
            permswap(a0, c0); permswap(b0, d0);
            U pb0; pb0.u[0]=a0; pb0.u[1]=b0; pb0.u[2]=c0; pb0.u[3]=d0;
            oB = __builtin_amdgcn_mfma_f32_32x32x16_f16(va0, pb0.v, oB, 0, 0, 0);
            unsigned e0 = pack2h(pB[8], pB[9]),   f0 = pack2h(pB[10], pB[11]);
            unsigned g0 = pack2h(pB[12], pB[13]), h0 = pack2h(pB[14], pB[15]);
            permswap(e0, g0); permswap(f0, h0);
            U pb1; pb1.u[0]=e0; pb1.u[1]=f0; pb1.u[2]=g0; pb1.u[3]=h0;
            oB = __builtin_amdgcn_mfma_f32_32x32x16_f16(va1, pb1.v, oB, 0, 0, 0);
        }
    }

    lsA += __shfl_xor(lsA, 32);
    lsB += __shfl_xor(lsB, 32);

    if (qrowA < N_SEQ) {
        const size_t qi = (size_t)h * N_SEQ + qrowA;
        if (hi == 0) {
            pm[(size_t)z * HN + qi] = mA;
            pl[(size_t)z * HN + qi] = lsA;
        }
        float* pa = pacc + ((size_t)z * HN + qi) * 32;
#pragma unroll
        for (int r = 0; r < 16; ++r)
            pa[(r & 3) + 8 * (r >> 2) + 4 * hi] = oA[r];
    }
    if (qrowB < N_SEQ) {
        const size_t qi = (size_t)h * N_SEQ + qrowB;
        if (hi == 0) {
            pm[(size_t)z * HN + qi] = mB;
            pl[(size_t)z * HN + qi] = lsB;
        }
        float* pa = pacc + ((size_t)z * HN + qi) * 32;
#pragma unroll
        for (int r = 0; r < 16; ++r)
            pa[(r & 3) + 8 * (r >> 2) + 4 * hi] = oB[r];
    }
}

// ---------------------------------------------------------------------------
// Merge key-split partials (max-merge, log2 domain) -> at_t[n][c] f16
// ---------------------------------------------------------------------------
__global__ __launch_bounds__(256) void merge_kernel(
    const float* __restrict__ pm, const float* __restrict__ pl,
    const float* __restrict__ pacc, unsigned short* __restrict__ at_t, int nz)
{
    const int idx = blockIdx.x * 256 + threadIdx.x;
    if (idx >= HN) return;
    const int h = idx / N_SEQ;
    const int n = idx - h * N_SEQ;

    float mg = pm[idx];
    for (int zz = 1; zz < nz; ++zz) mg = fmaxf(mg, pm[(size_t)zz * HN + idx]);

    float lg = 0.f;
    float acc[32];
#pragma unroll
    for (int d = 0; d < 32; ++d) acc[d] = 0.f;
    for (int zz = 0; zz < nz; ++zz) {
        const float e = exp2f(pm[(size_t)zz * HN + idx] - mg);
        lg += pl[(size_t)zz * HN + idx] * e;
        const float* pa = pacc + ((size_t)zz * HN + idx) * 32;
#pragma unroll
        for (int d = 0; d < 32; ++d) acc[d] = fmaf(pa[d], e, acc[d]);
    }
    const float inv = 1.0f / lg;
    union { unsigned short s[32]; uint4 u[4]; } ph;
#pragma unroll
    for (int d = 0; d < 32; ++d) ph.s[d] = f16b(acc[d] * inv);
    uint4* dst = (uint4*)(at_t + (size_t)n * C_IN + h * 32);
#pragma unroll
    for (int i = 0; i < 4; ++i) dst[i] = ph.u[i];
}

// ---------------------------------------------------------------------------
// proj_mfma: out[oc][n] = p_w . at + p_b. Split-K dual chain. f32 out.
// grid: 260 x 256
// ---------------------------------------------------------------------------
__global__ __launch_bounds__(256) void proj_mfma(
    const unsigned short* __restrict__ at_t, const unsigned short* __restrict__ pwf,
    const float* __restrict__ p_b, float* __restrict__ out)
{
    const int tid = threadIdx.x, wid = tid >> 6, lane = tid & 63;
    const int col = lane & 31, hi = lane >> 5;
    const int tile = blockIdx.x * 4 + wid;       // 0..1039
    const int ot = tile / NT32, nt = tile % NT32;
    const int n0 = nt * 32;

    const unsigned short* arow = pwf + (size_t)(ot * 32 + col) * C_IN + hi * 8;
    const unsigned short* brow = at_t + (size_t)(n0 + col) * C_IN + hi * 8;

    const float* pb4 = p_b + ot * 32 + 4 * hi;
    const float4 c0 = *(const float4*)(pb4);
    const float4 c1 = *(const float4*)(pb4 + 8);
    const float4 c2 = *(const float4*)(pb4 + 16);
    const float4 c3 = *(const float4*)(pb4 + 24);
    f32x16 acca, accb;
    acca[0]=c0.x; acca[1]=c0.y; acca[2]=c0.z; acca[3]=c0.w;
    acca[4]=c1.x; acca[5]=c1.y; acca[6]=c1.z; acca[7]=c1.w;
    acca[8]=c2.x; acca[9]=c2.y; acca[10]=c2.z; acca[11]=c2.w;
    acca[12]=c3.x; acca[13]=c3.y; acca[14]=c3.z; acca[15]=c3.w;
#pragma unroll
    for (int r = 0; r < 16; ++r) accb[r] = 0.f;

#pragma unroll
    for (int t = 0; t < 8; ++t) {
        const f16x8 afa = *(const f16x8*)(const void*)(arow + t * 16);
        const f16x8 bfa = *(const f16x8*)(const void*)(brow + t * 16);
        const f16x8 afb = *(const f16x8*)(const void*)(arow + (t + 8) * 16);
        const f16x8 bfb = *(const f16x8*)(const void*)(brow + (t + 8) * 16);
        acca = __builtin_amdgcn_mfma_f32_32x32x16_f16(afa, bfa, acca, 0, 0, 0);
        accb = __builtin_amdgcn_mfma_f32_32x32x16_f16(afb, bfb, accb, 0, 0, 0);
    }

    const int n = n0 + col;
    if (n < N_SEQ) {
#pragma unroll
        for (int r = 0; r < 16; ++r) {
            const int oc = ot * 32 + (r & 3) + 8 * (r >> 2) + 4 * hi;
            out[(size_t)oc * N_SEQ + n] = acca[r] + accb[r];
        }
    }
}

extern "C" void kernel_launch(void* const* d_in, const int* in_sizes, int n_in,
                              void* d_out, int out_size, void* d_ws, size_t ws_size,
                              hipStream_t stream) {
    const float* query  = (const float*)d_in[0];
    const float* q_w    = (const float*)d_in[1];
    const float* q_b    = (const float*)d_in[2];
    const float* k_w    = (const float*)d_in[3];
    const float* k_b    = (const float*)d_in[4];
    const float* v_w    = (const float*)d_in[5];
    const float* v_b    = (const float*)d_in[6];
    const float* p_w    = (const float*)d_in[7];
    const float* p_b    = (const float*)d_in[8];
    const float* log_qw = (const float*)d_in[9];

    const size_t HNP32 = (size_t)HEADS * NP * 32;    // 1,064,960

    unsigned short* xt  = (unsigned short*)d_ws;     // NP*256
    unsigned short* qb  = xt + (size_t)NP * C_IN;    // HNP32
    unsigned short* kb  = qb + HNP32;
    unsigned short* vb  = kb + HNP32;                // tiled V
    unsigned short* wf  = vb + HNP32;                // 768*256
    unsigned short* pwf = wf + 768 * 256;            // 256*256
    float* lw2 = (float*)(pwf + 256 * 256);          // NP
    float* pm  = lw2 + NP;
    unsigned short* at_t = qb;                       // alias: qb dead after attn

    const size_t base_bytes = (size_t)((char*)pm - (char*)d_ws);
    const size_t per_z = (size_t)HN * 34 * sizeof(float);
    int nz = 1;
    if      (ws_size >= base_bytes + 4 * per_z) nz = 4;
    else if (ws_size >= base_bytes + 2 * per_z) nz = 2;
    const int tiles_per_z = (NT32 + nz - 1) / nz;

    float* pl   = pm + (size_t)nz * HN;
    float* pacc = pl + (size_t)nz * HN;

    prep_kernel<<<dim3(NT32 + 3, 8), 256, 0, stream>>>(
        query, log_qw, q_w, k_w, v_w, p_w, xt, lw2, wf, pwf);

    qkv_mfma<<<dim3(390), 256, 0, stream>>>(
        xt, wf, q_b, k_b, v_b, qb, kb, vb);

    attn_mfma_kernel<<<dim3(130, nz), 256, 0, stream>>>(
        qb, kb, vb, lw2, pm, pl, pacc, tiles_per_z);

    merge_kernel<<<dim3((HN + 255) / 256), 256, 0, stream>>>(
        pm, pl, pacc, at_t, nz);

    proj_mfma<<<dim3(260), 256, 0, stream>>>(
        at_t, pwf, p_b, (float*)d_out);
}

// Round 11
// 171.552 us; speedup vs baseline: 1.0550x; 1.0550x over previous
//
#include <hip/hip_runtime.h>

#define N_SEQ 4140
#define NP    4160          // padded N (130*32)
#define C_IN  256
#define HEADS 8
#define NT32  130
#define HN    (HEADS * N_SEQ)
#define LOG2E 1.4426950408889634f
#define SCALE2 (0.17677669529663687f * LOG2E)   // (1/sqrt(32)) * log2e

typedef _Float16 f16x8 __attribute__((ext_vector_type(8)));
typedef _Float16 f16x2 __attribute__((ext_vector_type(2)));
typedef float    f32x16 __attribute__((ext_vector_type(16)));

__device__ inline unsigned short f16b(float x) {
    union { _Float16 h; unsigned short s; } c;
    c.h = (_Float16)x;
    return c.s;
}
__device__ inline f16x2 pkrtz(float a, float b) {
    auto r = __builtin_amdgcn_cvt_pkrtz(a, b);   // __fp16 ext_vector(2)
    union { decltype(r) i; f16x2 o; } c;
    c.i = r;
    return c.o;
}
__device__ inline void permswap(unsigned &a, unsigned &b) {
    asm volatile("v_permlane32_swap_b32 %0, %1" : "+v"(a), "+v"(b));
}

// ---------------------------------------------------------------------------
// prep: blocks x<130: x[c][n] f32 -> xt[n][c] f16 (zero-pad n>=N_SEQ).
//       blocks x>=130: weights f16 (q_w pre-scaled by SCALE2), lw2 = log_qw*log2e
// grid: (133, 8) x 256
// ---------------------------------------------------------------------------
__global__ __launch_bounds__(256) void prep_kernel(
    const float* __restrict__ x, const float* __restrict__ log_qw,
    const float* __restrict__ q_w, const float* __restrict__ k_w,
    const float* __restrict__ v_w, const float* __restrict__ p_w,
    unsigned short* __restrict__ xt, float* __restrict__ lw2,
    unsigned short* __restrict__ wf, unsigned short* __restrict__ pwf)
{
    if (blockIdx.x < NT32) {
        __shared__ unsigned short tile[32][33];
        const int tx = threadIdx.x & 31, ty = threadIdx.x >> 5;
        const int n0 = blockIdx.x * 32, c0 = blockIdx.y * 32;
#pragma unroll
        for (int i = 0; i < 4; ++i) {
            const int c = c0 + ty * 4 + i;
            const int n = n0 + tx;
            const float v = (n < N_SEQ) ? x[(size_t)c * N_SEQ + n] : 0.f;
            tile[tx][ty * 4 + i] = f16b(v);
        }
        __syncthreads();
#pragma unroll
        for (int i = 0; i < 4; ++i) {
            const int nl = ty * 4 + i;
            xt[(size_t)(n0 + nl) * C_IN + c0 + tx] = tile[nl][tx];
        }
    } else {
        const int bid = (blockIdx.x - NT32) * 8 + blockIdx.y;   // 0..23
        for (int i = bid * 256 + threadIdx.x; i < 262144 + NP; i += 24 * 256) {
            if (i < 65536)        wf[i] = f16b(q_w[i] * SCALE2);
            else if (i < 131072)  wf[i] = f16b(k_w[i - 65536]);
            else if (i < 196608)  wf[i] = f16b(v_w[i - 131072]);
            else if (i < 262144)  pwf[i - 196608] = f16b(p_w[i - 196608]);
            else {
                const int j = i - 262144;
                lw2[j] = (j < N_SEQ) ? log_qw[j] * LOG2E : -1e30f;
            }
        }
    }
}

// ---------------------------------------------------------------------------
// qkv_mfma: 24 oc-tiles x 65 n-pair-tiles, 1 wave each; two independent
// 16-MFMA chains sharing one operand. q (pre-scaled), k -> [h][n][32] ;
// v -> [((h*130+t)*32+d)*32+klocal].  grid: 390 x 256
// ---------------------------------------------------------------------------
__global__ __launch_bounds__(256) void qkv_mfma(
    const unsigned short* __restrict__ xt, const unsigned short* __restrict__ wf,
    const float* __restrict__ q_b, const float* __restrict__ k_b,
    const float* __restrict__ v_b,
    unsigned short* __restrict__ qo, unsigned short* __restrict__ ko,
    unsigned short* __restrict__ vo)
{
    const int tid = threadIdx.x, wid = tid >> 6, lane = tid & 63;
    const int col = lane & 31, hi = lane >> 5;
    const int w = blockIdx.x * 4 + wid;          // 0..1559
    const int ot = w / 65, pt = w % 65;
    const int n0 = pt * 64, n1 = n0 + 32;

    if (ot < 16) {
        const unsigned short* a0 = xt + (size_t)(n0 + col) * C_IN + hi * 8;
        const unsigned short* a1 = xt + (size_t)(n1 + col) * C_IN + hi * 8;
        const unsigned short* bw = wf + (size_t)(ot * 32 + col) * C_IN + hi * 8;
        const float bias = (ot < 8) ? q_b[ot * 32 + col] * SCALE2
                                    : k_b[(ot - 8) * 32 + col];
        f32x16 acc0, acc1;
#pragma unroll
        for (int r = 0; r < 16; ++r) { acc0[r] = bias; acc1[r] = bias; }
#pragma unroll
        for (int t = 0; t < 16; ++t) {
            const f16x8 bf  = *(const f16x8*)(const void*)(bw + t * 16);
            const f16x8 af0 = *(const f16x8*)(const void*)(a0 + t * 16);
            const f16x8 af1 = *(const f16x8*)(const void*)(a1 + t * 16);
            acc0 = __builtin_amdgcn_mfma_f32_32x32x16_f16(af0, bf, acc0, 0, 0, 0);
            acc1 = __builtin_amdgcn_mfma_f32_32x32x16_f16(af1, bf, acc1, 0, 0, 0);
        }
        unsigned short* dst = (ot < 8) ? qo : ko;
        const int h = ot & 7;
#pragma unroll
        for (int r = 0; r < 16; ++r) {
            const int rl = (r & 3) + 8 * (r >> 2) + 4 * hi;
            dst[(size_t)(h * NP + n0 + rl) * 32 + col] = f16b(acc0[r]);
            dst[(size_t)(h * NP + n1 + rl) * 32 + col] = f16b(acc1[r]);
        }
    } else {
        const int h = ot - 16;
        const unsigned short* aw = wf + (size_t)(512 + h * 32 + col) * C_IN + hi * 8;
        const unsigned short* b0 = xt + (size_t)(n0 + col) * C_IN + hi * 8;
        const unsigned short* b1 = xt + (size_t)(n1 + col) * C_IN + hi * 8;
        const float* vb4 = v_b + h * 32 + 4 * hi;
        const float4 c0 = *(const float4*)(vb4);
        const float4 c1 = *(const float4*)(vb4 + 8);
        const float4 c2 = *(const float4*)(vb4 + 16);
        const float4 c3 = *(const float4*)(vb4 + 24);
        f32x16 acc0;
        acc0[0]=c0.x; acc0[1]=c0.y; acc0[2]=c0.z; acc0[3]=c0.w;
        acc0[4]=c1.x; acc0[5]=c1.y; acc0[6]=c1.z; acc0[7]=c1.w;
        acc0[8]=c2.x; acc0[9]=c2.y; acc0[10]=c2.z; acc0[11]=c2.w;
        acc0[12]=c3.x; acc0[13]=c3.y; acc0[14]=c3.z; acc0[15]=c3.w;
        f32x16 acc1 = acc0;
#pragma unroll
        for (int t = 0; t < 16; ++t) {
            const f16x8 af  = *(const f16x8*)(const void*)(aw + t * 16);
            const f16x8 bf0 = *(const f16x8*)(const void*)(b0 + t * 16);
            const f16x8 bf1 = *(const f16x8*)(const void*)(b1 + t * 16);
            acc0 = __builtin_amdgcn_mfma_f32_32x32x16_f16(af, bf0, acc0, 0, 0, 0);
            acc1 = __builtin_amdgcn_mfma_f32_32x32x16_f16(af, bf1, acc1, 0, 0, 0);
        }
        const int nt0 = pt * 2, nt1 = nt0 + 1;
#pragma unroll
        for (int r = 0; r < 16; ++r) {
            const int d = (r & 3) + 8 * (r >> 2) + 4 * hi;
            vo[((size_t)(h * NT32 + nt0) * 32 + d) * 32 + col] = f16b(acc0[r]);
            vo[((size_t)(h * NT32 + nt1) * 32 + d) * 32 + col] = f16b(acc1[r]);
        }
    }
}

// ---------------------------------------------------------------------------
// MFMA flash attention. Q pre-scaled, lw2 (log2 units) as MFMA C-init ->
// scores come out of the MFMA ready for exp2. Defer-max (thr 8, log2),
// max3-style trees, cvt_pkrtz pack, fdot2 row-sum, permlane32_swap exchange.
// Two q-tiles per wave. grid: (130, nz) x 256
// ---------------------------------------------------------------------------
__global__ __launch_bounds__(256) void attn_mfma_kernel(
    const unsigned short* __restrict__ qb, const unsigned short* __restrict__ kb,
    const unsigned short* __restrict__ vb, const float* __restrict__ lw2,
    float* __restrict__ pm, float* __restrict__ pl, float* __restrict__ pacc,
    int tiles_per_z)
{
    const int tid = threadIdx.x;
    const int wid = tid >> 6;
    const int lane = tid & 63;
    const int col = lane & 31;
    const int hi = lane >> 5;
    const int job = blockIdx.x * 4 + wid;   // 0..519
    const int h = job / 65;
    const int pt = job % 65;
    const int z = blockIdx.y;

    const int qrowA = pt * 64 + col;
    const int qrowB = qrowA + 32;
    const unsigned short* qpA = qb + ((size_t)(h * NP + qrowA)) * 32 + hi * 8;
    const unsigned short* qpB = qb + ((size_t)(h * NP + qrowB)) * 32 + hi * 8;
    const f16x8 qfA0 = *(const f16x8*)(const void*)(qpA);
    const f16x8 qfA1 = *(const f16x8*)(const void*)(qpA + 16);
    const f16x8 qfB0 = *(const f16x8*)(const void*)(qpB);
    const f16x8 qfB1 = *(const f16x8*)(const void*)(qpB + 16);

    f32x16 oA, oB;
#pragma unroll
    for (int r = 0; r < 16; ++r) { oA[r] = 0.f; oB[r] = 0.f; }
    float mA = -1e30f, lsA = 0.f;
    float mB = -1e30f, lsB = 0.f;
    const f16x2 one2 = { (_Float16)1.f, (_Float16)1.f };

    const int t0 = z * tiles_per_z;
    const int t1 = min(NT32, t0 + tiles_per_z);
    const unsigned short* kbase = kb + (size_t)h * NP * 32;
    const unsigned short* vbase = vb + (size_t)h * NT32 * 1024;

    for (int t = t0; t < t1; ++t) {
        const int k0 = t * 32;
        const unsigned short* kp = kbase + (size_t)(k0 + col) * 32 + hi * 8;
        const f16x8 ka0 = *(const f16x8*)(const void*)(kp);
        const f16x8 ka1 = *(const f16x8*)(const void*)(kp + 16);
        const unsigned short* vp = vbase + (size_t)t * 1024 + col * 32 + hi * 8;
        const f16x8 va0 = *(const f16x8*)(const void*)(vp);
        const f16x8 va1 = *(const f16x8*)(const void*)(vp + 16);

        // C-init = log2-domain quadrature bias (Q carries the scale)
        const float* lw4 = lw2 + k0 + 4 * hi;
        const float4 w0 = *(const float4*)(lw4);
        const float4 w1 = *(const float4*)(lw4 + 8);
        const float4 w2 = *(const float4*)(lw4 + 16);
        const float4 w3 = *(const float4*)(lw4 + 24);
        f32x16 sA;
        sA[0]=w0.x; sA[1]=w0.y; sA[2]=w0.z; sA[3]=w0.w;
        sA[4]=w1.x; sA[5]=w1.y; sA[6]=w1.z; sA[7]=w1.w;
        sA[8]=w2.x; sA[9]=w2.y; sA[10]=w2.z; sA[11]=w2.w;
        sA[12]=w3.x; sA[13]=w3.y; sA[14]=w3.z; sA[15]=w3.w;
        f32x16 sB = sA;

        sA = __builtin_amdgcn_mfma_f32_32x32x16_f16(ka0, qfA0, sA, 0, 0, 0);
        sB = __builtin_amdgcn_mfma_f32_32x32x16_f16(ka0, qfB0, sB, 0, 0, 0);
        sA = __builtin_amdgcn_mfma_f32_32x32x16_f16(ka1, qfA1, sA, 0, 0, 0);
        sB = __builtin_amdgcn_mfma_f32_32x32x16_f16(ka1, qfB1, sB, 0, 0, 0);

        // max trees (max3-fusable triples)
        const float a0m = fmaxf(fmaxf(sA[0], sA[1]), sA[2]);
        const float a1m = fmaxf(fmaxf(sA[3], sA[4]), sA[5]);
        const float a2m = fmaxf(fmaxf(sA[6], sA[7]), sA[8]);
        const float a3m = fmaxf(fmaxf(sA[9], sA[10]), sA[11]);
        const float a4m = fmaxf(fmaxf(sA[12], sA[13]), sA[14]);
        const float cmaxA = fmaxf(fmaxf(fmaxf(a0m, a1m), a2m),
                                  fmaxf(fmaxf(a3m, a4m), sA[15]));
        const float b0m = fmaxf(fmaxf(sB[0], sB[1]), sB[2]);
        const float b1m = fmaxf(fmaxf(sB[3], sB[4]), sB[5]);
        const float b2m = fmaxf(fmaxf(sB[6], sB[7]), sB[8]);
        const float b3m = fmaxf(fmaxf(sB[9], sB[10]), sB[11]);
        const float b4m = fmaxf(fmaxf(sB[12], sB[13]), sB[14]);
        const float cmaxB = fmaxf(fmaxf(fmaxf(b0m, b1m), b2m),
                                  fmaxf(fmaxf(b3m, b4m), sB[15]));

        if (!__all(cmaxA - mA <= 8.0f)) {
            float cw = fmaxf(cmaxA, __shfl_xor(cmaxA, 32));
            const float mnew = fmaxf(mA, cw);
            const float esc = __builtin_amdgcn_exp2f(mA - mnew);
            lsA *= esc;
#pragma unroll
            for (int r = 0; r < 16; ++r) oA[r] *= esc;
            mA = mnew;
        }
        if (!__all(cmaxB - mB <= 8.0f)) {
            float cw = fmaxf(cmaxB, __shfl_xor(cmaxB, 32));
            const float mnew = fmaxf(mB, cw);
            const float esc = __builtin_amdgcn_exp2f(mB - mnew);
            lsB *= esc;
#pragma unroll
            for (int r = 0; r < 16; ++r) oB[r] *= esc;
            mB = mnew;
        }

        float pA[16], pB[16];
#pragma unroll
        for (int r = 0; r < 16; ++r) {
            pA[r] = __builtin_amdgcn_exp2f(sA[r] - mA);
            pB[r] = __builtin_amdgcn_exp2f(sB[r] - mB);
        }

        union PK { f16x2 h[4]; unsigned u[4]; f16x8 v; };
        // stream A
        {
            PK k0p, k1p;
            k0p.h[0] = pkrtz(pA[0], pA[1]);
            k0p.h[1] = pkrtz(pA[2], pA[3]);
            k0p.h[2] = pkrtz(pA[4], pA[5]);
            k0p.h[3] = pkrtz(pA[6], pA[7]);
            k1p.h[0] = pkrtz(pA[8], pA[9]);
            k1p.h[1] = pkrtz(pA[10], pA[11]);
            k1p.h[2] = pkrtz(pA[12], pA[13]);
            k1p.h[3] = pkrtz(pA[14], pA[15]);
            float sa = __builtin_amdgcn_fdot2(k0p.h[0], one2, 0.f, false);
            float sb = __builtin_amdgcn_fdot2(k0p.h[1], one2, 0.f, false);
            sa = __builtin_amdgcn_fdot2(k0p.h[2], one2, sa, false);
            sb = __builtin_amdgcn_fdot2(k0p.h[3], one2, sb, false);
            sa = __builtin_amdgcn_fdot2(k1p.h[0], one2, sa, false);
            sb = __builtin_amdgcn_fdot2(k1p.h[1], one2, sb, false);
            sa = __builtin_amdgcn_fdot2(k1p.h[2], one2, sa, false);
            sb = __builtin_amdgcn_fdot2(k1p.h[3], one2, sb, false);
            lsA += sa + sb;
            permswap(k0p.u[0], k0p.u[2]);
            permswap(k0p.u[1], k0p.u[3]);
            oA = __builtin_amdgcn_mfma_f32_32x32x16_f16(va0, k0p.v, oA, 0, 0, 0);
            permswap(k1p.u[0], k1p.u[2]);
            permswap(k1p.u[1], k1p.u[3]);
            oA = __builtin_amdgcn_mfma_f32_32x32x16_f16(va1, k1p.v, oA, 0, 0, 0);
        }
        // stream B
        {
            PK k0p, k1p;
            k0p.h[0] = pkrtz(pB[0], pB[1]);
            k0p.h[1] = pkrtz(pB[2], pB[3]);
            k0p.h[2] = pkrtz(pB[4], pB[5]);
            k0p.h[3] = pkrtz(pB[6], pB[7]);
            k1p.h[0] = pkrtz(pB[8], pB[9]);
            k1p.h[1] = pkrtz(pB[10], pB[11]);
            k1p.h[2] = pkrtz(pB[12], pB[13]);
            k1p.h[3] = pkrtz(pB[14], pB[15]);
            float sa = __builtin_amdgcn_fdot2(k0p.h[0], one2, 0.f, false);
            float sb = __builtin_amdgcn_fdot2(k0p.h[1], one2, 0.f, false);
            sa = __builtin_amdgcn_fdot2(k0p.h[2], one2, sa, false);
            sb = __builtin_amdgcn_fdot2(k0p.h[3], one2, sb, false);
            sa = __builtin_amdgcn_fdot2(k1p.h[0], one2, sa, false);
            sb = __builtin_amdgcn_fdot2(k1p.h[1], one2, sb, false);
            sa = __builtin_amdgcn_fdot2(k1p.h[2], one2, sa, false);
            sb = __builtin_amdgcn_fdot2(k1p.h[3], one2, sb, false);
            lsB += sa + sb;
            permswap(k0p.u[0], k0p.u[2]);
            permswap(k0p.u[1], k0p.u[3]);
            oB = __builtin_amdgcn_mfma_f32_32x32x16_f16(va0, k0p.v, oB, 0, 0, 0);
            permswap(k1p.u[0], k1p.u[2]);
            permswap(k1p.u[1], k1p.u[3]);
            oB = __builtin_amdgcn_mfma_f32_32x32x16_f16(va1, k1p.v, oB, 0, 0, 0);
        }
    }

    lsA += __shfl_xor(lsA, 32);
    lsB += __shfl_xor(lsB, 32);

    if (qrowA < N_SEQ) {
        const size_t qi = (size_t)h * N_SEQ + qrowA;
        if (hi == 0) {
            pm[(size_t)z * HN + qi] = mA;
            pl[(size_t)z * HN + qi] = lsA;
        }
        float* pa = pacc + ((size_t)z * HN + qi) * 32;
#pragma unroll
        for (int r = 0; r < 16; ++r)
            pa[(r & 3) + 8 * (r >> 2) + 4 * hi] = oA[r];
    }
    if (qrowB < N_SEQ) {
        const size_t qi = (size_t)h * N_SEQ + qrowB;
        if (hi == 0) {
            pm[(size_t)z * HN + qi] = mB;
            pl[(size_t)z * HN + qi] = lsB;
        }
        float* pa = pacc + ((size_t)z * HN + qi) * 32;
#pragma unroll
        for (int r = 0; r < 16; ++r)
            pa[(r & 3) + 8 * (r >> 2) + 4 * hi] = oB[r];
    }
}

// ---------------------------------------------------------------------------
// Merge key-split partials (max-merge, log2 domain) -> at_t[n][c] f16
// ---------------------------------------------------------------------------
__global__ __launch_bounds__(256) void merge_kernel(
    const float* __restrict__ pm, const float* __restrict__ pl,
    const float* __restrict__ pacc, unsigned short* __restrict__ at_t, int nz)
{
    const int idx = blockIdx.x * 256 + threadIdx.x;
    if (idx >= HN) return;
    const int h = idx / N_SEQ;
    const int n = idx - h * N_SEQ;

    float mg = pm[idx];
    for (int zz = 1; zz < nz; ++zz) mg = fmaxf(mg, pm[(size_t)zz * HN + idx]);

    float lg = 0.f;
    float acc[32];
#pragma unroll
    for (int d = 0; d < 32; ++d) acc[d] = 0.f;
    for (int zz = 0; zz < nz; ++zz) {
        const float e = exp2f(pm[(size_t)zz * HN + idx] - mg);
        lg += pl[(size_t)zz * HN + idx] * e;
        const float* pa = pacc + ((size_t)zz * HN + idx) * 32;
#pragma unroll
        for (int d = 0; d < 32; ++d) acc[d] = fmaf(pa[d], e, acc[d]);
    }
    const float inv = 1.0f / lg;
    union { unsigned short s[32]; uint4 u[4]; } ph;
#pragma unroll
    for (int d = 0; d < 32; ++d) ph.s[d] = f16b(acc[d] * inv);
    uint4* dst = (uint4*)(at_t + (size_t)n * C_IN + h * 32);
#pragma unroll
    for (int i = 0; i < 4; ++i) dst[i] = ph.u[i];
}

// ---------------------------------------------------------------------------
// proj_mfma: out[oc][n] = p_w . at + p_b. Split-K dual chain. f32 out.
// grid: 260 x 256
// ---------------------------------------------------------------------------
__global__ __launch_bounds__(256) void proj_mfma(
    const unsigned short* __restrict__ at_t, const unsigned short* __restrict__ pwf,
    const float* __restrict__ p_b, float* __restrict__ out)
{
    const int tid = threadIdx.x, wid = tid >> 6, lane = tid & 63;
    const int col = lane & 31, hi = lane >> 5;
    const int tile = blockIdx.x * 4 + wid;       // 0..1039
    const int ot = tile / NT32, nt = tile % NT32;
    const int n0 = nt * 32;

    const unsigned short* arow = pwf + (size_t)(ot * 32 + col) * C_IN + hi * 8;
    const unsigned short* brow = at_t + (size_t)(n0 + col) * C_IN + hi * 8;

    const float* pb4 = p_b + ot * 32 + 4 * hi;
    const float4 c0 = *(const float4*)(pb4);
    const float4 c1 = *(const float4*)(pb4 + 8);
    const float4 c2 = *(const float4*)(pb4 + 16);
    const float4 c3 = *(const float4*)(pb4 + 24);
    f32x16 acca, accb;
    acca[0]=c0.x; acca[1]=c0.y; acca[2]=c0.z; acca[3]=c0.w;
    acca[4]=c1.x; acca[5]=c1.y; acca[6]=c1.z; acca[7]=c1.w;
    acca[8]=c2.x; acca[9]=c2.y; acca[10]=c2.z; acca[11]=c2.w;
    acca[12]=c3.x; acca[13]=c3.y; acca[14]=c3.z; acca[15]=c3.w;
#pragma unroll
    for (int r = 0; r < 16; ++r) accb[r] = 0.f;

#pragma unroll
    for (int t = 0; t < 8; ++t) {
        const f16x8 afa = *(const f16x8*)(const void*)(arow + t * 16);
        const f16x8 bfa = *(const f16x8*)(const void*)(brow + t * 16);
        const f16x8 afb = *(const f16x8*)(const void*)(arow + (t + 8) * 16);
        const f16x8 bfb = *(const f16x8*)(const void*)(brow + (t + 8) * 16);
        acca = __builtin_amdgcn_mfma_f32_32x32x16_f16(afa, bfa, acca, 0, 0, 0);
        accb = __builtin_amdgcn_mfma_f32_32x32x16_f16(afb, bfb, accb, 0, 0, 0);
    }

    const int n = n0 + col;
    if (n < N_SEQ) {
#pragma unroll
        for (int r = 0; r < 16; ++r) {
            const int oc = ot * 32 + (r & 3) + 8 * (r >> 2) + 4 * hi;
            out[(size_t)oc * N_SEQ + n] = acca[r] + accb[r];
        }
    }
}

extern "C" void kernel_launch(void* const* d_in, const int* in_sizes, int n_in,
                              void* d_out, int out_size, void* d_ws, size_t ws_size,
                              hipStream_t stream) {
    const float* query  = (const float*)d_in[0];
    const float* q_w    = (const float*)d_in[1];
    const float* q_b    = (const float*)d_in[2];
    const float* k_w    = (const float*)d_in[3];
    const float* k_b    = (const float*)d_in[4];
    const float* v_w    = (const float*)d_in[5];
    const float* v_b    = (const float*)d_in[6];
    const float* p_w    = (const float*)d_in[7];
    const float* p_b    = (const float*)d_in[8];
    const float* log_qw = (const float*)d_in[9];

    const size_t HNP32 = (size_t)HEADS * NP * 32;    // 1,064,960

    unsigned short* xt  = (unsigned short*)d_ws;     // NP*256
    unsigned short* qb  = xt + (size_t)NP * C_IN;    // HNP32
    unsigned short* kb  = qb + HNP32;
    unsigned short* vb  = kb + HNP32;                // tiled V
    unsigned short* wf  = vb + HNP32;                // 768*256
    unsigned short* pwf = wf + 768 * 256;            // 256*256
    float* lw2 = (float*)(pwf + 256 * 256);          // NP
    float* pm  = lw2 + NP;
    unsigned short* at_t = qb;                       // alias: qb dead after attn

    const size_t base_bytes = (size_t)((char*)pm - (char*)d_ws);
    const size_t per_z = (size_t)HN * 34 * sizeof(float);
    int nz = 1;
    if      (ws_size >= base_bytes + 8 * per_z) nz = 8;
    else if (ws_size >= base_bytes + 4 * per_z) nz = 4;
    else if (ws_size >= base_bytes + 2 * per_z) nz = 2;
    const int tiles_per_z = (NT32 + nz - 1) / nz;

    float* pl   = pm + (size_t)nz * HN;
    float* pacc = pl + (size_t)nz * HN;

    prep_kernel<<<dim3(NT32 + 3, 8), 256, 0, stream>>>(
        query, log_qw, q_w, k_w, v_w, p_w, xt, lw2, wf, pwf);

    qkv_mfma<<<dim3(390), 256, 0, stream>>>(
        xt, wf, q_b, k_b, v_b, qb, kb, vb);

    attn_mfma_kernel<<<dim3(130, nz), 256, 0, stream>>>(
        qb, kb, vb, lw2, pm, pl, pacc, tiles_per_z);

    merge_kernel<<<dim3((HN + 255) / 256), 256, 0, stream>>>(
        pm, pl, pacc, at_t, nz);

    proj_mfma<<<dim3(260), 256, 0, stream>>>(
        at_t, pwf, p_b, (float*)d_out);
}

// Round 12
// 163.971 us; speedup vs baseline: 1.1038x; 1.0462x over previous
//
#include <hip/hip_runtime.h>

#define N_SEQ 4140
#define NP    4160          // padded N (130*32)
#define C_IN  256
#define HEADS 8
#define NT32  130
#define HN    (HEADS * N_SEQ)
#define LOG2E 1.4426950408889634f
#define SCALE2 (0.17677669529663687f * LOG2E)   // (1/sqrt(32)) * log2e

typedef _Float16 f16x8 __attribute__((ext_vector_type(8)));
typedef _Float16 f16x2 __attribute__((ext_vector_type(2)));
typedef float    f32x16 __attribute__((ext_vector_type(16)));

__device__ inline unsigned short f16b(float x) {
    union { _Float16 h; unsigned short s; } c;
    c.h = (_Float16)x;
    return c.s;
}
__device__ inline f16x2 pkrtz(float a, float b) {
    auto r = __builtin_amdgcn_cvt_pkrtz(a, b);   // __fp16 ext_vector(2)
    union { decltype(r) i; f16x2 o; } c;
    c.i = r;
    return c.o;
}
__device__ inline void permswap(unsigned &a, unsigned &b) {
    asm volatile("v_permlane32_swap_b32 %0, %1" : "+v"(a), "+v"(b));
}

// ---------------------------------------------------------------------------
// prep: blocks x<130: x[c][n] f32 -> xt[n][c] f16 (zero-pad n>=N_SEQ).
//       blocks x>=130: weights f16 (q_w pre-scaled by SCALE2), lw2 = log_qw*log2e
// grid: (133, 8) x 256
// ---------------------------------------------------------------------------
__global__ __launch_bounds__(256) void prep_kernel(
    const float* __restrict__ x, const float* __restrict__ log_qw,
    const float* __restrict__ q_w, const float* __restrict__ k_w,
    const float* __restrict__ v_w, const float* __restrict__ p_w,
    unsigned short* __restrict__ xt, float* __restrict__ lw2,
    unsigned short* __restrict__ wf, unsigned short* __restrict__ pwf)
{
    if (blockIdx.x < NT32) {
        __shared__ unsigned short tile[32][33];
        const int tx = threadIdx.x & 31, ty = threadIdx.x >> 5;
        const int n0 = blockIdx.x * 32, c0 = blockIdx.y * 32;
#pragma unroll
        for (int i = 0; i < 4; ++i) {
            const int c = c0 + ty * 4 + i;
            const int n = n0 + tx;
            const float v = (n < N_SEQ) ? x[(size_t)c * N_SEQ + n] : 0.f;
            tile[tx][ty * 4 + i] = f16b(v);
        }
        __syncthreads();
#pragma unroll
        for (int i = 0; i < 4; ++i) {
            const int nl = ty * 4 + i;
            xt[(size_t)(n0 + nl) * C_IN + c0 + tx] = tile[nl][tx];
        }
    } else {
        const int bid = (blockIdx.x - NT32) * 8 + blockIdx.y;   // 0..23
        for (int i = bid * 256 + threadIdx.x; i < 262144 + NP; i += 24 * 256) {
            if (i < 65536)        wf[i] = f16b(q_w[i] * SCALE2);
            else if (i < 131072)  wf[i] = f16b(k_w[i - 65536]);
            else if (i < 196608)  wf[i] = f16b(v_w[i - 131072]);
            else if (i < 262144)  pwf[i - 196608] = f16b(p_w[i - 196608]);
            else {
                const int j = i - 262144;
                lw2[j] = (j < N_SEQ) ? log_qw[j] * LOG2E : -1e30f;
            }
        }
    }
}

// ---------------------------------------------------------------------------
// qkv_mfma: one 32x32 output tile per 64-thread block (wave). Dual
// independent K-chains (t 0..7 / 8..15) for ILP. q (pre-scaled), k ->
// [h][n][32] ; v -> [((h*130+nt)*32+d)*32+klocal].  grid: 3120 x 64
// ---------------------------------------------------------------------------
__global__ __launch_bounds__(64) void qkv_mfma(
    const unsigned short* __restrict__ xt, const unsigned short* __restrict__ wf,
    const float* __restrict__ q_b, const float* __restrict__ k_b,
    const float* __restrict__ v_b,
    unsigned short* __restrict__ qo, unsigned short* __restrict__ ko,
    unsigned short* __restrict__ vo)
{
    const int lane = threadIdx.x;
    const int col = lane & 31, hi = lane >> 5;
    const int bid = blockIdx.x;                  // 0..3119
    const int ot = bid / NT32, nt = bid % NT32;
    const int n0 = nt * 32;

    if (ot < 16) {
        const unsigned short* arow = xt + (size_t)(n0 + col) * C_IN + hi * 8;
        const unsigned short* brow = wf + (size_t)(ot * 32 + col) * C_IN + hi * 8;
        const float bias = (ot < 8) ? q_b[ot * 32 + col] * SCALE2
                                    : k_b[(ot - 8) * 32 + col];
        f32x16 acc0, acc1;
#pragma unroll
        for (int r = 0; r < 16; ++r) { acc0[r] = bias; acc1[r] = 0.f; }
#pragma unroll
        for (int t = 0; t < 8; ++t) {
            const f16x8 af0 = *(const f16x8*)(const void*)(arow + t * 16);
            const f16x8 bf0 = *(const f16x8*)(const void*)(brow + t * 16);
            const f16x8 af1 = *(const f16x8*)(const void*)(arow + (t + 8) * 16);
            const f16x8 bf1 = *(const f16x8*)(const void*)(brow + (t + 8) * 16);
            acc0 = __builtin_amdgcn_mfma_f32_32x32x16_f16(af0, bf0, acc0, 0, 0, 0);
            acc1 = __builtin_amdgcn_mfma_f32_32x32x16_f16(af1, bf1, acc1, 0, 0, 0);
        }
        unsigned short* dst = (ot < 8) ? qo : ko;
        const int h = ot & 7;
#pragma unroll
        for (int r = 0; r < 16; ++r) {
            const int rl = (r & 3) + 8 * (r >> 2) + 4 * hi;
            dst[(size_t)(h * NP + n0 + rl) * 32 + col] = f16b(acc0[r] + acc1[r]);
        }
    } else {
        const int h = ot - 16;
        const unsigned short* arow = wf + (size_t)(512 + h * 32 + col) * C_IN + hi * 8;
        const unsigned short* brow = xt + (size_t)(n0 + col) * C_IN + hi * 8;
        const float* vb4 = v_b + h * 32 + 4 * hi;
        const float4 c0 = *(const float4*)(vb4);
        const float4 c1 = *(const float4*)(vb4 + 8);
        const float4 c2 = *(const float4*)(vb4 + 16);
        const float4 c3 = *(const float4*)(vb4 + 24);
        f32x16 acc0, acc1;
        acc0[0]=c0.x; acc0[1]=c0.y; acc0[2]=c0.z; acc0[3]=c0.w;
        acc0[4]=c1.x; acc0[5]=c1.y; acc0[6]=c1.z; acc0[7]=c1.w;
        acc0[8]=c2.x; acc0[9]=c2.y; acc0[10]=c2.z; acc0[11]=c2.w;
        acc0[12]=c3.x; acc0[13]=c3.y; acc0[14]=c3.z; acc0[15]=c3.w;
#pragma unroll
        for (int r = 0; r < 16; ++r) acc1[r] = 0.f;
#pragma unroll
        for (int t = 0; t < 8; ++t) {
            const f16x8 af0 = *(const f16x8*)(const void*)(arow + t * 16);
            const f16x8 bf0 = *(const f16x8*)(const void*)(brow + t * 16);
            const f16x8 af1 = *(const f16x8*)(const void*)(arow + (t + 8) * 16);
            const f16x8 bf1 = *(const f16x8*)(const void*)(brow + (t + 8) * 16);
            acc0 = __builtin_amdgcn_mfma_f32_32x32x16_f16(af0, bf0, acc0, 0, 0, 0);
            acc1 = __builtin_amdgcn_mfma_f32_32x32x16_f16(af1, bf1, acc1, 0, 0, 0);
        }
#pragma unroll
        for (int r = 0; r < 16; ++r) {
            const int d = (r & 3) + 8 * (r >> 2) + 4 * hi;
            vo[((size_t)(h * NT32 + nt) * 32 + d) * 32 + col] = f16b(acc0[r] + acc1[r]);
        }
    }
}

// ---------------------------------------------------------------------------
// MFMA flash attention (unchanged math from round 11). 64-thr blocks,
// grid (520, nz); wave = (head, q-pair-tile), two q-streams per wave.
// ---------------------------------------------------------------------------
__global__ __launch_bounds__(64) void attn_mfma_kernel(
    const unsigned short* __restrict__ qb, const unsigned short* __restrict__ kb,
    const unsigned short* __restrict__ vb, const float* __restrict__ lw2,
    float* __restrict__ pm, float* __restrict__ pl, float* __restrict__ pacc,
    int tiles_per_z)
{
    const int lane = threadIdx.x;
    const int col = lane & 31;
    const int hi = lane >> 5;
    const int job = blockIdx.x;             // 0..519
    const int h = job / 65;
    const int pt = job % 65;
    const int z = blockIdx.y;

    const int qrowA = pt * 64 + col;
    const int qrowB = qrowA + 32;
    const unsigned short* qpA = qb + ((size_t)(h * NP + qrowA)) * 32 + hi * 8;
    const unsigned short* qpB = qb + ((size_t)(h * NP + qrowB)) * 32 + hi * 8;
    const f16x8 qfA0 = *(const f16x8*)(const void*)(qpA);
    const f16x8 qfA1 = *(const f16x8*)(const void*)(qpA + 16);
    const f16x8 qfB0 = *(const f16x8*)(const void*)(qpB);
    const f16x8 qfB1 = *(const f16x8*)(const void*)(qpB + 16);

    f32x16 oA, oB;
#pragma unroll
    for (int r = 0; r < 16; ++r) { oA[r] = 0.f; oB[r] = 0.f; }
    float mA = -1e30f, lsA = 0.f;
    float mB = -1e30f, lsB = 0.f;
    const f16x2 one2 = { (_Float16)1.f, (_Float16)1.f };

    const int t0 = z * tiles_per_z;
    const int t1 = min(NT32, t0 + tiles_per_z);
    const unsigned short* kbase = kb + (size_t)h * NP * 32;
    const unsigned short* vbase = vb + (size_t)h * NT32 * 1024;

    for (int t = t0; t < t1; ++t) {
        const int k0 = t * 32;
        const unsigned short* kp = kbase + (size_t)(k0 + col) * 32 + hi * 8;
        const f16x8 ka0 = *(const f16x8*)(const void*)(kp);
        const f16x8 ka1 = *(const f16x8*)(const void*)(kp + 16);
        const unsigned short* vp = vbase + (size_t)t * 1024 + col * 32 + hi * 8;
        const f16x8 va0 = *(const f16x8*)(const void*)(vp);
        const f16x8 va1 = *(const f16x8*)(const void*)(vp + 16);

        const float* lw4 = lw2 + k0 + 4 * hi;
        const float4 w0 = *(const float4*)(lw4);
        const float4 w1 = *(const float4*)(lw4 + 8);
        const float4 w2 = *(const float4*)(lw4 + 16);
        const float4 w3 = *(const float4*)(lw4 + 24);
        f32x16 sA;
        sA[0]=w0.x; sA[1]=w0.y; sA[2]=w0.z; sA[3]=w0.w;
        sA[4]=w1.x; sA[5]=w1.y; sA[6]=w1.z; sA[7]=w1.w;
        sA[8]=w2.x; sA[9]=w2.y; sA[10]=w2.z; sA[11]=w2.w;
        sA[12]=w3.x; sA[13]=w3.y; sA[14]=w3.z; sA[15]=w3.w;
        f32x16 sB = sA;

        sA = __builtin_amdgcn_mfma_f32_32x32x16_f16(ka0, qfA0, sA, 0, 0, 0);
        sB = __builtin_amdgcn_mfma_f32_32x32x16_f16(ka0, qfB0, sB, 0, 0, 0);
        sA = __builtin_amdgcn_mfma_f32_32x32x16_f16(ka1, qfA1, sA, 0, 0, 0);
        sB = __builtin_amdgcn_mfma_f32_32x32x16_f16(ka1, qfB1, sB, 0, 0, 0);

        const float a0m = fmaxf(fmaxf(sA[0], sA[1]), sA[2]);
        const float a1m = fmaxf(fmaxf(sA[3], sA[4]), sA[5]);
        const float a2m = fmaxf(fmaxf(sA[6], sA[7]), sA[8]);
        const float a3m = fmaxf(fmaxf(sA[9], sA[10]), sA[11]);
        const float a4m = fmaxf(fmaxf(sA[12], sA[13]), sA[14]);
        const float cmaxA = fmaxf(fmaxf(fmaxf(a0m, a1m), a2m),
                                  fmaxf(fmaxf(a3m, a4m), sA[15]));
        const float b0m = fmaxf(fmaxf(sB[0], sB[1]), sB[2]);
        const float b1m = fmaxf(fmaxf(sB[3], sB[4]), sB[5]);
        const float b2m = fmaxf(fmaxf(sB[6], sB[7]), sB[8]);
        const float b3m = fmaxf(fmaxf(sB[9], sB[10]), sB[11]);
        const float b4m = fmaxf(fmaxf(sB[12], sB[13]), sB[14]);
        const float cmaxB = fmaxf(fmaxf(fmaxf(b0m, b1m), b2m),
                                  fmaxf(fmaxf(b3m, b4m), sB[15]));

        if (!__all(cmaxA - mA <= 8.0f)) {
            float cw = fmaxf(cmaxA, __shfl_xor(cmaxA, 32));
            const float mnew = fmaxf(mA, cw);
            const float esc = __builtin_amdgcn_exp2f(mA - mnew);
            lsA *= esc;
#pragma unroll
            for (int r = 0; r < 16; ++r) oA[r] *= esc;
            mA = mnew;
        }
        if (!__all(cmaxB - mB <= 8.0f)) {
            float cw = fmaxf(cmaxB, __shfl_xor(cmaxB, 32));
            const float mnew = fmaxf(mB, cw);
            const float esc = __builtin_amdgcn_exp2f(mB - mnew);
            lsB *= esc;
#pragma unroll
            for (int r = 0; r < 16; ++r) oB[r] *= esc;
            mB = mnew;
        }

        float pA[16], pB[16];
#pragma unroll
        for (int r = 0; r < 16; ++r) {
            pA[r] = __builtin_amdgcn_exp2f(sA[r] - mA);
            pB[r] = __builtin_amdgcn_exp2f(sB[r] - mB);
        }

        union PK { f16x2 h[4]; unsigned u[4]; f16x8 v; };
        {
            PK k0p, k1p;
            k0p.h[0] = pkrtz(pA[0], pA[1]);
            k0p.h[1] = pkrtz(pA[2], pA[3]);
            k0p.h[2] = pkrtz(pA[4], pA[5]);
            k0p.h[3] = pkrtz(pA[6], pA[7]);
            k1p.h[0] = pkrtz(pA[8], pA[9]);
            k1p.h[1] = pkrtz(pA[10], pA[11]);
            k1p.h[2] = pkrtz(pA[12], pA[13]);
            k1p.h[3] = pkrtz(pA[14], pA[15]);
            float sa = __builtin_amdgcn_fdot2(k0p.h[0], one2, 0.f, false);
            float sb = __builtin_amdgcn_fdot2(k0p.h[1], one2, 0.f, false);
            sa = __builtin_amdgcn_fdot2(k0p.h[2], one2, sa, false);
            sb = __builtin_amdgcn_fdot2(k0p.h[3], one2, sb, false);
            sa = __builtin_amdgcn_fdot2(k1p.h[0], one2, sa, false);
            sb = __builtin_amdgcn_fdot2(k1p.h[1], one2, sb, false);
            sa = __builtin_amdgcn_fdot2(k1p.h[2], one2, sa, false);
            sb = __builtin_amdgcn_fdot2(k1p.h[3], one2, sb, false);
            lsA += sa + sb;
            permswap(k0p.u[0], k0p.u[2]);
            permswap(k0p.u[1], k0p.u[3]);
            oA = __builtin_amdgcn_mfma_f32_32x32x16_f16(va0, k0p.v, oA, 0, 0, 0);
            permswap(k1p.u[0], k1p.u[2]);
            permswap(k1p.u[1], k1p.u[3]);
            oA = __builtin_amdgcn_mfma_f32_32x32x16_f16(va1, k1p.v, oA, 0, 0, 0);
        }
        {
            PK k0p, k1p;
            k0p.h[0] = pkrtz(pB[0], pB[1]);
            k0p.h[1] = pkrtz(pB[2], pB[3]);
            k0p.h[2] = pkrtz(pB[4], pB[5]);
            k0p.h[3] = pkrtz(pB[6], pB[7]);
            k1p.h[0] = pkrtz(pB[8], pB[9]);
            k1p.h[1] = pkrtz(pB[10], pB[11]);
            k1p.h[2] = pkrtz(pB[12], pB[13]);
            k1p.h[3] = pkrtz(pB[14], pB[15]);
            float sa = __builtin_amdgcn_fdot2(k0p.h[0], one2, 0.f, false);
            float sb = __builtin_amdgcn_fdot2(k0p.h[1], one2, 0.f, false);
            sa = __builtin_amdgcn_fdot2(k0p.h[2], one2, sa, false);
            sb = __builtin_amdgcn_fdot2(k0p.h[3], one2, sb, false);
            sa = __builtin_amdgcn_fdot2(k1p.h[0], one2, sa, false);
            sb = __builtin_amdgcn_fdot2(k1p.h[1], one2, sb, false);
            sa = __builtin_amdgcn_fdot2(k1p.h[2], one2, sa, false);
            sb = __builtin_amdgcn_fdot2(k1p.h[3], one2, sb, false);
            lsB += sa + sb;
            permswap(k0p.u[0], k0p.u[2]);
            permswap(k0p.u[1], k0p.u[3]);
            oB = __builtin_amdgcn_mfma_f32_32x32x16_f16(va0, k0p.v, oB, 0, 0, 0);
            permswap(k1p.u[0], k1p.u[2]);
            permswap(k1p.u[1], k1p.u[3]);
            oB = __builtin_amdgcn_mfma_f32_32x32x16_f16(va1, k1p.v, oB, 0, 0, 0);
        }
    }

    lsA += __shfl_xor(lsA, 32);
    lsB += __shfl_xor(lsB, 32);

    if (qrowA < N_SEQ) {
        const size_t qi = (size_t)h * N_SEQ + qrowA;
        if (hi == 0) {
            pm[(size_t)z * HN + qi] = mA;
            pl[(size_t)z * HN + qi] = lsA;
        }
        float* pa = pacc + ((size_t)z * HN + qi) * 32;
#pragma unroll
        for (int r = 0; r < 16; ++r)
            pa[(r & 3) + 8 * (r >> 2) + 4 * hi] = oA[r];
    }
    if (qrowB < N_SEQ) {
        const size_t qi = (size_t)h * N_SEQ + qrowB;
        if (hi == 0) {
            pm[(size_t)z * HN + qi] = mB;
            pl[(size_t)z * HN + qi] = lsB;
        }
        float* pa = pacc + ((size_t)z * HN + qi) * 32;
#pragma unroll
        for (int r = 0; r < 16; ++r)
            pa[(r & 3) + 8 * (r >> 2) + 4 * hi] = oB[r];
    }
}

// ---------------------------------------------------------------------------
// Merge key-split partials (max-merge, log2 domain) -> at_t[n][c] f16.
// 4 threads per query (each owns 8 d's); lg recomputed per sub-thread.
// grid: ceil(HN*4/256) x 256
// ---------------------------------------------------------------------------
__global__ __launch_bounds__(256) void merge_kernel(
    const float* __restrict__ pm, const float* __restrict__ pl,
    const float* __restrict__ pacc, unsigned short* __restrict__ at_t, int nz)
{
    const int gid = blockIdx.x * 256 + threadIdx.x;
    if (gid >= HN * 4) return;
    const int idx = gid >> 2;
    const int sub = gid & 3;
    const int h = idx / N_SEQ;
    const int n = idx - h * N_SEQ;

    float mg = pm[idx];
    for (int zz = 1; zz < nz; ++zz) mg = fmaxf(mg, pm[(size_t)zz * HN + idx]);

    float lg = 0.f;
    float acc[8];
#pragma unroll
    for (int d = 0; d < 8; ++d) acc[d] = 0.f;
    for (int zz = 0; zz < nz; ++zz) {
        const float e = exp2f(pm[(size_t)zz * HN + idx] - mg);
        lg += pl[(size_t)zz * HN + idx] * e;
        const float* pa = pacc + ((size_t)zz * HN + idx) * 32 + sub * 8;
#pragma unroll
        for (int d = 0; d < 8; ++d) acc[d] = fmaf(pa[d], e, acc[d]);
    }
    const float inv = 1.0f / lg;
    union { unsigned short s[8]; uint4 u; } ph;
#pragma unroll
    for (int d = 0; d < 8; ++d) ph.s[d] = f16b(acc[d] * inv);
    *(uint4*)(at_t + (size_t)n * C_IN + h * 32 + sub * 8) = ph.u;
}

// ---------------------------------------------------------------------------
// proj_mfma: out[oc][n] = p_w . at + p_b. Split-K dual chain. f32 out.
// grid: 1040 x 64 (one tile per wave)
// ---------------------------------------------------------------------------
__global__ __launch_bounds__(64) void proj_mfma(
    const unsigned short* __restrict__ at_t, const unsigned short* __restrict__ pwf,
    const float* __restrict__ p_b, float* __restrict__ out)
{
    const int lane = threadIdx.x;
    const int col = lane & 31, hi = lane >> 5;
    const int tile = blockIdx.x;                 // 0..1039
    const int ot = tile / NT32, nt = tile % NT32;
    const int n0 = nt * 32;

    const unsigned short* arow = pwf + (size_t)(ot * 32 + col) * C_IN + hi * 8;
    const unsigned short* brow = at_t + (size_t)(n0 + col) * C_IN + hi * 8;

    const float* pb4 = p_b + ot * 32 + 4 * hi;
    const float4 c0 = *(const float4*)(pb4);
    const float4 c1 = *(const float4*)(pb4 + 8);
    const float4 c2 = *(const float4*)(pb4 + 16);
    const float4 c3 = *(const float4*)(pb4 + 24);
    f32x16 acca, accb;
    acca[0]=c0.x; acca[1]=c0.y; acca[2]=c0.z; acca[3]=c0.w;
    acca[4]=c1.x; acca[5]=c1.y; acca[6]=c1.z; acca[7]=c1.w;
    acca[8]=c2.x; acca[9]=c2.y; acca[10]=c2.z; acca[11]=c2.w;
    acca[12]=c3.x; acca[13]=c3.y; acca[14]=c3.z; acca[15]=c3.w;
#pragma unroll
    for (int r = 0; r < 16; ++r) accb[r] = 0.f;

#pragma unroll
    for (int t = 0; t < 8; ++t) {
        const f16x8 afa = *(const f16x8*)(const void*)(arow + t * 16);
        const f16x8 bfa = *(const f16x8*)(const void*)(brow + t * 16);
        const f16x8 afb = *(const f16x8*)(const void*)(arow + (t + 8) * 16);
        const f16x8 bfb = *(const f16x8*)(const void*)(brow + (t + 8) * 16);
        acca = __builtin_amdgcn_mfma_f32_32x32x16_f16(afa, bfa, acca, 0, 0, 0);
        accb = __builtin_amdgcn_mfma_f32_32x32x16_f16(afb, bfb, accb, 0, 0, 0);
    }

    const int n = n0 + col;
    if (n < N_SEQ) {
#pragma unroll
        for (int r = 0; r < 16; ++r) {
            const int oc = ot * 32 + (r & 3) + 8 * (r >> 2) + 4 * hi;
            out[(size_t)oc * N_SEQ + n] = acca[r] + accb[r];
        }
    }
}

extern "C" void kernel_launch(void* const* d_in, const int* in_sizes, int n_in,
                              void* d_out, int out_size, void* d_ws, size_t ws_size,
                              hipStream_t stream) {
    const float* query  = (const float*)d_in[0];
    const float* q_w    = (const float*)d_in[1];
    const float* q_b    = (const float*)d_in[2];
    const float* k_w    = (const float*)d_in[3];
    const float* k_b    = (const float*)d_in[4];
    const float* v_w    = (const float*)d_in[5];
    const float* v_b    = (const float*)d_in[6];
    const float* p_w    = (const float*)d_in[7];
    const float* p_b    = (const float*)d_in[8];
    const float* log_qw = (const float*)d_in[9];

    const size_t HNP32 = (size_t)HEADS * NP * 32;    // 1,064,960

    unsigned short* xt  = (unsigned short*)d_ws;     // NP*256
    unsigned short* qb  = xt + (size_t)NP * C_IN;    // HNP32
    unsigned short* kb  = qb + HNP32;
    unsigned short* vb  = kb + HNP32;                // tiled V
    unsigned short* wf  = vb + HNP32;                // 768*256
    unsigned short* pwf = wf + 768 * 256;            // 256*256
    float* lw2 = (float*)(pwf + 256 * 256);          // NP
    float* pm  = lw2 + NP;
    unsigned short* at_t = qb;                       // alias: qb dead after attn

    const size_t base_bytes = (size_t)((char*)pm - (char*)d_ws);
    const size_t per_z = (size_t)HN * 34 * sizeof(float);
    int nz = 1;
    if      (ws_size >= base_bytes + 8 * per_z) nz = 8;
    else if (ws_size >= base_bytes + 4 * per_z) nz = 4;
    else if (ws_size >= base_bytes + 2 * per_z) nz = 2;
    const int tiles_per_z = (NT32 + nz - 1) / nz;

    float* pl   = pm + (size_t)nz * HN;
    float* pacc = pl + (size_t)nz * HN;

    prep_kernel<<<dim3(NT32 + 3, 8), 256, 0, stream>>>(
        query, log_qw, q_w, k_w, v_w, p_w, xt, lw2, wf, pwf);

    qkv_mfma<<<dim3(3120), 64, 0, stream>>>(
        xt, wf, q_b, k_b, v_b, qb, kb, vb);

    attn_mfma_kernel<<<dim3(520, nz), 64, 0, stream>>>(
        qb, kb, vb, lw2, pm, pl, pacc, tiles_per_z);

    merge_kernel<<<dim3((HN * 4 + 255) / 256), 256, 0, stream>>>(
        pm, pl, pacc, at_t, nz);

    proj_mfma<<<dim3(1040), 64, 0, stream>>>(
        at_t, pwf, p_b, (float*)d_out);
}